// Round 1
// baseline (123.933 us; speedup 1.0000x reference)
//
#include <hip/hip_runtime.h>

// score[b] = (sum_src[b] . sum_tar[b]) / (cnt_src[b] * cnt_tar[b])
// Inputs: x_src [N_SRC,256] f32, batch_src [N_SRC] i32 (sorted),
//         x_tar [N_TAR,256] f32, batch_tar [N_TAR] i32 (sorted)
// Output: score [512] f32

#define DIM 256
#define NSEG 512

// Each 64-lane subgroup owns 64 contiguous rows; lane l owns cols [4l,4l+4).
// Sorted batch ids -> accumulate in registers, flush with atomics only at
// segment boundaries (~2 flushes / 64-row chunk at avg seg len ~390).
__global__ __launch_bounds__(256) void seg_sum_kernel(
    const float* __restrict__ x, const int* __restrict__ batch,
    int n_rows, float* __restrict__ sums, float* __restrict__ cnts)
{
    const int lane  = threadIdx.x & 63;
    const int group = threadIdx.x >> 6;                 // 0..3 subgroups/block
    const int rowBase = (blockIdx.x * 4 + group) * 64;
    if (rowBase >= n_rows) return;

    // one coalesced load of this chunk's batch ids; broadcast later via shfl
    int myb = -1;
    if (rowBase + lane < n_rows) myb = batch[rowBase + lane];

    float4 acc = make_float4(0.f, 0.f, 0.f, 0.f);
    int cur = -1;
    int run = 0;
    const int nr = (n_rows - rowBase < 64) ? (n_rows - rowBase) : 64;

    for (int r = 0; r < nr; ++r) {
        const int b = __shfl(myb, r, 64);
        if (b != cur) {
            if (cur >= 0) {
                float* s = sums + (size_t)cur * DIM + lane * 4;
                atomicAdd(s + 0, acc.x);
                atomicAdd(s + 1, acc.y);
                atomicAdd(s + 2, acc.z);
                atomicAdd(s + 3, acc.w);
                if (lane == 0) atomicAdd(cnts + cur, (float)run);
            }
            cur = b;
            run = 0;
            acc = make_float4(0.f, 0.f, 0.f, 0.f);
        }
        const float4 v = *reinterpret_cast<const float4*>(
            x + (size_t)(rowBase + r) * DIM + lane * 4);
        acc.x += v.x; acc.y += v.y; acc.z += v.z; acc.w += v.w;
        ++run;
    }
    if (cur >= 0) {
        float* s = sums + (size_t)cur * DIM + lane * 4;
        atomicAdd(s + 0, acc.x);
        atomicAdd(s + 1, acc.y);
        atomicAdd(s + 2, acc.z);
        atomicAdd(s + 3, acc.w);
        if (lane == 0) atomicAdd(cnts + cur, (float)run);
    }
}

// One wave per segment: dot(sum_src[b], sum_tar[b]) / (cnt_src[b]*cnt_tar[b])
__global__ __launch_bounds__(64) void score_kernel(
    const float* __restrict__ sum_src, const float* __restrict__ sum_tar,
    const float* __restrict__ cnt_src, const float* __restrict__ cnt_tar,
    float* __restrict__ out)
{
    const int b    = blockIdx.x;
    const int lane = threadIdx.x;
    const float4 s = *reinterpret_cast<const float4*>(sum_src + (size_t)b * DIM + lane * 4);
    const float4 t = *reinterpret_cast<const float4*>(sum_tar + (size_t)b * DIM + lane * 4);
    float dot = s.x * t.x + s.y * t.y + s.z * t.z + s.w * t.w;
    #pragma unroll
    for (int off = 32; off > 0; off >>= 1)
        dot += __shfl_down(dot, off, 64);
    if (lane == 0)
        out[b] = dot / (cnt_src[b] * cnt_tar[b]);
}

extern "C" void kernel_launch(void* const* d_in, const int* in_sizes, int n_in,
                              void* d_out, int out_size, void* d_ws, size_t ws_size,
                              hipStream_t stream) {
    const float* x_src = (const float*)d_in[0];
    const int*   b_src = (const int*)  d_in[1];
    const float* x_tar = (const float*)d_in[2];
    const int*   b_tar = (const int*)  d_in[3];
    const int n_src = in_sizes[1];
    const int n_tar = in_sizes[3];
    float* out = (float*)d_out;

    float* sum_src = (float*)d_ws;                 // [NSEG, DIM]
    float* sum_tar = sum_src + (size_t)NSEG * DIM; // [NSEG, DIM]
    float* cnt_src = sum_tar + (size_t)NSEG * DIM; // [NSEG]
    float* cnt_tar = cnt_src + NSEG;               // [NSEG]

    const size_t zero_bytes = (size_t)(2 * NSEG * DIM + 2 * NSEG) * sizeof(float);
    hipMemsetAsync(d_ws, 0, zero_bytes, stream);

    const int rows_per_block = 256;                // 4 subgroups x 64 rows
    const int g_src = (n_src + rows_per_block - 1) / rows_per_block;
    const int g_tar = (n_tar + rows_per_block - 1) / rows_per_block;
    seg_sum_kernel<<<g_src, 256, 0, stream>>>(x_src, b_src, n_src, sum_src, cnt_src);
    seg_sum_kernel<<<g_tar, 256, 0, stream>>>(x_tar, b_tar, n_tar, sum_tar, cnt_tar);
    score_kernel<<<NSEG, 64, 0, stream>>>(sum_src, sum_tar, cnt_src, cnt_tar, out);
}

// Round 2
// 95.306 us; speedup vs baseline: 1.3004x; 1.3004x over previous
//
#include <hip/hip_runtime.h>

// score[b] = (sum_src[b] . sum_tar[b]) / (cnt_src[b] * cnt_tar[b])
// Inputs: x_src [N_SRC,256] f32, batch_src [N_SRC] i32 (sorted),
//         x_tar [N_TAR,256] f32, batch_tar [N_TAR] i32 (sorted)
// Output: score [512] f32

#define DIM 256
#define NSEG 512

// Zero 2*NSEG*DIM sums + 2*NSEG cnts = 263168 floats = 65792 float4.
// Own kernel instead of hipMemsetAsync: rocclr's small-fill path measured
// ~9 GB/s (118 us for 1 MB) -- a 257-block float4 store kernel is ~3 us.
__global__ __launch_bounds__(256) void zero_ws_kernel(float4* __restrict__ ws) {
    const unsigned i = blockIdx.x * 256u + threadIdx.x;
    if (i < (2u * NSEG * DIM + 2u * NSEG) / 4u)
        ws[i] = make_float4(0.f, 0.f, 0.f, 0.f);
}

// Fused segment-sum over both inputs in one launch (grid = blocks_src + blocks_tar).
// Each 64-lane wave owns 64 contiguous rows; lane l owns cols [4l, 4l+4).
// Sorted batch ids -> per-chunk boundary mask via ballot, then branch-free
// accumulate loops per run (usually 1-2 runs/chunk at avg seg len ~390),
// flushing to global sums with atomics only at run ends.
__global__ __launch_bounds__(256) void seg_sum_fused(
    const float* __restrict__ x_src, const int* __restrict__ batch_src, int n_src,
    const float* __restrict__ x_tar, const int* __restrict__ batch_tar, int n_tar,
    float* __restrict__ sums_src, float* __restrict__ cnts_src,
    float* __restrict__ sums_tar, float* __restrict__ cnts_tar,
    int blocks_src)
{
    const float* x;
    const int*   batch;
    float*       sums;
    float*       cnts;
    int          n_rows, blk;
    if ((int)blockIdx.x < blocks_src) {
        x = x_src; batch = batch_src; sums = sums_src; cnts = cnts_src;
        n_rows = n_src; blk = blockIdx.x;
    } else {
        x = x_tar; batch = batch_tar; sums = sums_tar; cnts = cnts_tar;
        n_rows = n_tar; blk = blockIdx.x - blocks_src;
    }

    const int lane    = threadIdx.x & 63;
    const int group   = threadIdx.x >> 6;            // 4 waves/block
    const int rowBase = (blk * 4 + group) * 64;
    if (rowBase >= n_rows) return;
    const int nr = (n_rows - rowBase < 64) ? (n_rows - rowBase) : 64;

    // lane l holds batch id of row rowBase+l (coalesced int load)
    const int myb   = (lane < nr) ? batch[rowBase + lane] : -1;
    const int prevb = __shfl_up(myb, 1, 64);         // lane 0: own value back
    unsigned long long bmask =
        __ballot(lane < nr && (lane == 0 || myb != prevb));

    while (bmask) {
        const int start = __ffsll(bmask) - 1;
        bmask &= bmask - 1;                          // clear lowest set bit
        const int end = bmask ? (__ffsll(bmask) - 1) : nr;
        const int b   = __shfl(myb, start, 64);

        float4 acc = make_float4(0.f, 0.f, 0.f, 0.f);
        const float* px = x + (size_t)(rowBase + start) * DIM + lane * 4;
        #pragma unroll 4
        for (int r = start; r < end; ++r, px += DIM) {
            const float4 v = *reinterpret_cast<const float4*>(px);
            acc.x += v.x; acc.y += v.y; acc.z += v.z; acc.w += v.w;
        }

        float* s = sums + (size_t)b * DIM + lane * 4;
        atomicAdd(s + 0, acc.x);
        atomicAdd(s + 1, acc.y);
        atomicAdd(s + 2, acc.z);
        atomicAdd(s + 3, acc.w);
        if (lane == 0) atomicAdd(cnts + b, (float)(end - start));
    }
}

// One wave per segment: dot(sum_src[b], sum_tar[b]) / (cnt_src[b]*cnt_tar[b])
__global__ __launch_bounds__(64) void score_kernel(
    const float* __restrict__ sum_src, const float* __restrict__ sum_tar,
    const float* __restrict__ cnt_src, const float* __restrict__ cnt_tar,
    float* __restrict__ out)
{
    const int b    = blockIdx.x;
    const int lane = threadIdx.x;
    const float4 s = *reinterpret_cast<const float4*>(sum_src + (size_t)b * DIM + lane * 4);
    const float4 t = *reinterpret_cast<const float4*>(sum_tar + (size_t)b * DIM + lane * 4);
    float dot = s.x * t.x + s.y * t.y + s.z * t.z + s.w * t.w;
    #pragma unroll
    for (int off = 32; off > 0; off >>= 1)
        dot += __shfl_down(dot, off, 64);
    if (lane == 0)
        out[b] = dot / (cnt_src[b] * cnt_tar[b]);
}

extern "C" void kernel_launch(void* const* d_in, const int* in_sizes, int n_in,
                              void* d_out, int out_size, void* d_ws, size_t ws_size,
                              hipStream_t stream) {
    const float* x_src = (const float*)d_in[0];
    const int*   b_src = (const int*)  d_in[1];
    const float* x_tar = (const float*)d_in[2];
    const int*   b_tar = (const int*)  d_in[3];
    const int n_src = in_sizes[1];
    const int n_tar = in_sizes[3];
    float* out = (float*)d_out;

    float* sum_src = (float*)d_ws;                 // [NSEG, DIM]
    float* sum_tar = sum_src + (size_t)NSEG * DIM; // [NSEG, DIM]
    float* cnt_src = sum_tar + (size_t)NSEG * DIM; // [NSEG]
    float* cnt_tar = cnt_src + NSEG;               // [NSEG]

    // zero kernel covers exactly (2*NSEG*DIM + 2*NSEG)/4 = 65792 float4s
    const int zero_blocks = (2 * NSEG * DIM + 2 * NSEG) / 4 / 256 + 1; // 257
    zero_ws_kernel<<<zero_blocks, 256, 0, stream>>>((float4*)d_ws);

    const int rows_per_block = 256;                // 4 waves x 64 rows
    const int g_src = (n_src + rows_per_block - 1) / rows_per_block;
    const int g_tar = (n_tar + rows_per_block - 1) / rows_per_block;
    seg_sum_fused<<<g_src + g_tar, 256, 0, stream>>>(
        x_src, b_src, n_src, x_tar, b_tar, n_tar,
        sum_src, cnt_src, sum_tar, cnt_tar, g_src);

    score_kernel<<<NSEG, 64, 0, stream>>>(sum_src, sum_tar, cnt_src, cnt_tar, out);
}

// Round 3
// 74.480 us; speedup vs baseline: 1.6640x; 1.2796x over previous
//
#include <hip/hip_runtime.h>

// score[b] = (sum_src[b] . sum_tar[b]) / (cnt_src[b] * cnt_tar[b])
// batch_src / batch_tar are SORTED -> segment b owns row range
// [lower_bound(b), lower_bound(b+1)) in each array. One block per segment:
// no atomics, no workspace, no zero kernel, single launch.

#define DIM  256
#define NSEG 512
#define NW   16          // waves per block
#define NT   (NW * 64)   // 1024 threads

// Cooperative 64-ary lower_bound: all 64 lanes probe, ballot picks the
// sub-range. Window shrinks ~64x/round: 200000 -> ~3126 -> ~50 -> ~2 -> 1.
__device__ __forceinline__ int lower_bound64(const int* __restrict__ a, int n,
                                             int key, int lane) {
    int LO = -1;   // invariant: a[LO] < key   (a[-1] = -inf)
    int HI = n;    // invariant: a[HI] >= key  (a[n]  = +inf)
    while (HI - LO > 1) {
        const int w   = HI - LO;
        const int pos = LO + 1 + (int)(((long long)(w - 1) * lane) >> 6);
        const bool pred = a[pos] < key;
        const unsigned long long mask = __ballot(pred);
        if (mask == 0ull) { HI = LO + 1; break; }
        const int kmax = 63 - __clzll(mask);
        const int nLO  = LO + 1 + (int)(((long long)(w - 1) * kmax) >> 6);
        const int nHI  = (kmax < 63)
                       ? (LO + 1 + (int)(((long long)(w - 1) * (kmax + 1)) >> 6))
                       : HI;
        LO = nLO; HI = nHI;
    }
    return HI;
}

__global__ __launch_bounds__(NT) void fused_score_kernel(
    const float* __restrict__ x_src, const int* __restrict__ batch_src, int n_src,
    const float* __restrict__ x_tar, const int* __restrict__ batch_tar, int n_tar,
    float* __restrict__ out)
{
    __shared__ int   bounds[4];
    __shared__ float red[NW][DIM];   // 16 KB

    const int seg  = blockIdx.x;
    const int tid  = threadIdx.x;
    const int lane = tid & 63;
    const int w    = tid >> 6;       // wave id 0..15

    // waves 0..3 each find one boundary
    if (w < 4) {
        const int* arr = (w < 2) ? batch_src : batch_tar;
        const int  n   = (w < 2) ? n_src : n_tar;
        const int  lb  = lower_bound64(arr, n, seg + (w & 1), lane);
        if (lane == 0) bounds[w] = lb;
    }
    __syncthreads();
    const int s0 = bounds[0], s1 = bounds[1];
    const int t0 = bounds[2], t1 = bounds[3];

    // each wave streams rows s0+w, s0+w+16, ... ; lane owns cols [4l, 4l+4)
    float4 aS = make_float4(0.f, 0.f, 0.f, 0.f);
    float4 aT = make_float4(0.f, 0.f, 0.f, 0.f);
    const float* ps = x_src + (size_t)lane * 4;
    #pragma unroll 4
    for (int r = s0 + w; r < s1; r += NW) {
        const float4 v = *reinterpret_cast<const float4*>(ps + (size_t)r * DIM);
        aS.x += v.x; aS.y += v.y; aS.z += v.z; aS.w += v.w;
    }
    const float* pt = x_tar + (size_t)lane * 4;
    #pragma unroll 4
    for (int r = t0 + w; r < t1; r += NW) {
        const float4 v = *reinterpret_cast<const float4*>(pt + (size_t)r * DIM);
        aT.x += v.x; aT.y += v.y; aT.z += v.z; aT.w += v.w;
    }

    // cross-wave reduce src sums
    *reinterpret_cast<float4*>(&red[w][lane * 4]) = aS;
    __syncthreads();
    float sumS = 0.f, sumT = 0.f;
    if (tid < DIM) {
        #pragma unroll
        for (int i = 0; i < NW; ++i) sumS += red[i][tid];
    }
    __syncthreads();

    // cross-wave reduce tar sums (reuse LDS)
    *reinterpret_cast<float4*>(&red[w][lane * 4]) = aT;
    __syncthreads();
    if (tid < DIM) {
        #pragma unroll
        for (int i = 0; i < NW; ++i) sumT += red[i][tid];
        red[0][tid] = sumS * sumT;   // per-column products
    }
    __syncthreads();

    // wave 0: reduce 256 products -> dot, scale by 1/(cnt_src*cnt_tar)
    if (w == 0) {
        float d = red[0][lane] + red[0][lane + 64]
                + red[0][lane + 128] + red[0][lane + 192];
        #pragma unroll
        for (int off = 32; off > 0; off >>= 1)
            d += __shfl_down(d, off, 64);
        if (lane == 0) {
            const float c = (float)(s1 - s0) * (float)(t1 - t0);
            out[seg] = d / c;
        }
    }
}

extern "C" void kernel_launch(void* const* d_in, const int* in_sizes, int n_in,
                              void* d_out, int out_size, void* d_ws, size_t ws_size,
                              hipStream_t stream) {
    const float* x_src = (const float*)d_in[0];
    const int*   b_src = (const int*)  d_in[1];
    const float* x_tar = (const float*)d_in[2];
    const int*   b_tar = (const int*)  d_in[3];
    const int n_src = in_sizes[1];
    const int n_tar = in_sizes[3];
    float* out = (float*)d_out;

    fused_score_kernel<<<NSEG, NT, 0, stream>>>(
        x_src, b_src, n_src, x_tar, b_tar, n_tar, out);
}